// Round 2
// baseline (107.228 us; speedup 1.0000x reference)
//
#include <hip/hip_runtime.h>
#include <hip/hip_bf16.h>

typedef __attribute__((ext_vector_type(8))) short bf16x8;
typedef __attribute__((ext_vector_type(4))) float f32x4;

__device__ __forceinline__ short f2b(float f) {
    __hip_bfloat16 h = __float2bfloat16(f);   // RNE
    return __builtin_bit_cast(short, h);
}

// Kernel 1: x f32 -> bf16, and y2 = 2*(x @ A^T) as bf16.
// grid 1024 x 256 threads.
__global__ void prep_kernel(const float* __restrict__ x,
                            const float* __restrict__ A,
                            ushort* __restrict__ xb,     // [64][4096] bf16
                            ushort* __restrict__ yb) {   // [64][64] bf16
    const int tid = threadIdx.x, bid = blockIdx.x;

    // part A: convert x (65536 float4's)
    const int gid = bid * 256 + tid;
    if (gid < 65536) {
        float4 v = ((const float4*)x)[gid];
        ushort4 s;
        s.x = (ushort)f2b(v.x); s.y = (ushort)f2b(v.y);
        s.z = (ushort)f2b(v.z); s.w = (ushort)f2b(v.w);
        ((ushort4*)xb)[gid] = s;
    }

    // part B: one wave per y2 output (4096 outputs total)
    const int wave = tid >> 6, lane = tid & 63;
    const int idx = bid * 4 + wave;          // 0..4095
    const int t = idx >> 6, r = idx & 63;
    const float4* xr = (const float4*)(x + (size_t)t * 4096);
    const float4* ar = (const float4*)(A + (size_t)r * 4096);
    float s = 0.f;
    #pragma unroll
    for (int i = 0; i < 16; ++i) {
        float4 a = xr[i * 64 + lane];
        float4 b = ar[i * 64 + lane];
        s += a.x * b.x + a.y * b.y + a.z * b.z + a.w * b.w;
    }
    #pragma unroll
    for (int off = 32; off; off >>= 1) s += __shfl_xor(s, off, 64);
    if (lane == 0) yb[idx] = (ushort)f2b(2.0f * s);
}

// Kernel 2: P[kc] = x@W^T over K-chunk kc (+ lora tail on kc==0).
// grid (1024, 4) x 64 threads: blockIdx.x = 16-col tile, blockIdx.y = K-chunk.
__global__ void __launch_bounds__(64)
lora_gemm(const float* __restrict__ W,      // [16384][4096]
          const float* __restrict__ Bm,     // [16384][64]
          const ushort* __restrict__ xb,    // [64][4096] bf16
          const ushort* __restrict__ yb,    // [64][64] bf16
          float* __restrict__ P) {          // [4][64][16384] partials
    const int lane = threadIdx.x;
    const int j0 = blockIdx.x << 4;
    const int kc = blockIdx.y;               // 0..3, K-chunk of 1024
    const int c  = lane & 15;                // B-frag col / A-frag row
    const int kg = lane >> 4;                // k-group: k offset = kg*8

    const float*  wr = W  + (size_t)(j0 + c) * 4096 + kc * 1024 + kg * 8;
    const ushort* x0 = xb + (size_t)c * 4096 + kc * 1024 + kg * 8;

    f32x4 acc0 = {0.f,0.f,0.f,0.f};
    f32x4 acc1 = acc0, acc2 = acc0, acc3 = acc0;

    #pragma unroll 4
    for (int k = 0; k < 1024; k += 32) {
        float4 w0 = *(const float4*)(wr + k);
        float4 w1 = *(const float4*)(wr + k + 4);
        bf16x8 b;
        b[0] = f2b(w0.x); b[1] = f2b(w0.y); b[2] = f2b(w0.z); b[3] = f2b(w0.w);
        b[4] = f2b(w1.x); b[5] = f2b(w1.y); b[6] = f2b(w1.z); b[7] = f2b(w1.w);
        bf16x8 a0 = *(const bf16x8*)(x0 + k);
        bf16x8 a1 = *(const bf16x8*)(x0 + 16 * 4096 + k);
        bf16x8 a2 = *(const bf16x8*)(x0 + 32 * 4096 + k);
        bf16x8 a3 = *(const bf16x8*)(x0 + 48 * 4096 + k);
        acc0 = __builtin_amdgcn_mfma_f32_16x16x32_bf16(a0, b, acc0, 0, 0, 0);
        acc1 = __builtin_amdgcn_mfma_f32_16x16x32_bf16(a1, b, acc1, 0, 0, 0);
        acc2 = __builtin_amdgcn_mfma_f32_16x16x32_bf16(a2, b, acc2, 0, 0, 0);
        acc3 = __builtin_amdgcn_mfma_f32_16x16x32_bf16(a3, b, acc3, 0, 0, 0);
    }

    if (kc == 0) {
        // lora tail: 2 more K-steps over r=64 with B matrix and y2
        const float*  br = Bm + (size_t)(j0 + c) * 64 + kg * 8;
        const ushort* y0 = yb + (size_t)c * 64 + kg * 8;
        #pragma unroll
        for (int k = 0; k < 64; k += 32) {
            float4 w0 = *(const float4*)(br + k);
            float4 w1 = *(const float4*)(br + k + 4);
            bf16x8 b;
            b[0] = f2b(w0.x); b[1] = f2b(w0.y); b[2] = f2b(w0.z); b[3] = f2b(w0.w);
            b[4] = f2b(w1.x); b[5] = f2b(w1.y); b[6] = f2b(w1.z); b[7] = f2b(w1.w);
            bf16x8 a0 = *(const bf16x8*)(y0 + k);
            bf16x8 a1 = *(const bf16x8*)(y0 + 16 * 64 + k);
            bf16x8 a2 = *(const bf16x8*)(y0 + 32 * 64 + k);
            bf16x8 a3 = *(const bf16x8*)(y0 + 48 * 64 + k);
            acc0 = __builtin_amdgcn_mfma_f32_16x16x32_bf16(a0, b, acc0, 0, 0, 0);
            acc1 = __builtin_amdgcn_mfma_f32_16x16x32_bf16(a1, b, acc1, 0, 0, 0);
            acc2 = __builtin_amdgcn_mfma_f32_16x16x32_bf16(a2, b, acc2, 0, 0, 0);
            acc3 = __builtin_amdgcn_mfma_f32_16x16x32_bf16(a3, b, acc3, 0, 0, 0);
        }
    }

    // store partials: D row = kg*4 + reg (within 16-token group), col = c
    float* op = P + (size_t)kc * 64 * 16384 + j0 + c;
    #pragma unroll
    for (int r = 0; r < 4; ++r) {
        op[(size_t)( 0 + kg * 4 + r) * 16384] = acc0[r];
        op[(size_t)(16 + kg * 4 + r) * 16384] = acc1[r];
        op[(size_t)(32 + kg * 4 + r) * 16384] = acc2[r];
        op[(size_t)(48 + kg * 4 + r) * 16384] = acc3[r];
    }
}

// Kernel 3: out = P0 + P1 + P2 + P3. 262144 float4's, grid 1024 x 256.
__global__ void reduce_kernel(const float4* __restrict__ P,
                              float4* __restrict__ out) {
    const int i = blockIdx.x * 256 + threadIdx.x;   // 0..262143
    float4 a = P[i];
    float4 b = P[i + 262144];
    float4 c = P[i + 524288];
    float4 d = P[i + 786432];
    float4 o;
    o.x = a.x + b.x + c.x + d.x;
    o.y = a.y + b.y + c.y + d.y;
    o.z = a.z + b.z + c.z + d.z;
    o.w = a.w + b.w + c.w + d.w;
    out[i] = o;
}

extern "C" void kernel_launch(void* const* d_in, const int* in_sizes, int n_in,
                              void* d_out, int out_size, void* d_ws, size_t ws_size,
                              hipStream_t stream) {
    const float* x  = (const float*)d_in[0];
    const float* W  = (const float*)d_in[1];
    const float* A  = (const float*)d_in[2];
    const float* Bm = (const float*)d_in[3];
    float* out = (float*)d_out;

    ushort* xb = (ushort*)d_ws;                          // 64*4096*2 = 524288 B
    ushort* yb = (ushort*)((char*)d_ws + 524288);        // 64*64*2   = 8192 B
    float*  P  = (float*)((char*)d_ws + (1 << 20));      // 4*64*16384*4 = 16 MiB

    prep_kernel<<<1024, 256, 0, stream>>>(x, A, xb, yb);
    lora_gemm<<<dim3(1024, 4), 64, 0, stream>>>(W, Bm, xb, yb, P);
    reduce_kernel<<<1024, 256, 0, stream>>>((const float4*)P, (float4*)out);
}

// Round 3
// 93.323 us; speedup vs baseline: 1.1490x; 1.1490x over previous
//
#include <hip/hip_runtime.h>
#include <hip/hip_bf16.h>

typedef __attribute__((ext_vector_type(8))) short bf16x8;
typedef __attribute__((ext_vector_type(4))) float f32x4;

__device__ __forceinline__ short f2b(float f) {
    __hip_bfloat16 h = __float2bfloat16(f);   // RNE
    return __builtin_bit_cast(short, h);
}

#define KT 256      // K-tile in floats (1 KB per row per stage)
#define NTILE 16    // 4096 / 256

// Kernel 1: x f32 -> bf16, and y2 = 2*(x @ A^T) as bf16.
__global__ void prep_kernel(const float* __restrict__ x,
                            const float* __restrict__ A,
                            ushort* __restrict__ xb,     // [64][4096] bf16
                            ushort* __restrict__ yb) {   // [64][64] bf16
    const int tid = threadIdx.x, bid = blockIdx.x;

    const int gid = bid * 256 + tid;
    if (gid < 65536) {
        float4 v = ((const float4*)x)[gid];
        ushort4 s;
        s.x = (ushort)f2b(v.x); s.y = (ushort)f2b(v.y);
        s.z = (ushort)f2b(v.z); s.w = (ushort)f2b(v.w);
        ((ushort4*)xb)[gid] = s;
    }

    const int wave = tid >> 6, lane = tid & 63;
    const int idx = bid * 4 + wave;          // 0..4095
    const int t = idx >> 6, r = idx & 63;
    const float4* xr = (const float4*)(x + (size_t)t * 4096);
    const float4* ar = (const float4*)(A + (size_t)r * 4096);
    float s = 0.f;
    #pragma unroll
    for (int i = 0; i < 16; ++i) {
        float4 a = xr[i * 64 + lane];
        float4 b = ar[i * 64 + lane];
        s += a.x * b.x + a.y * b.y + a.z * b.z + a.w * b.w;
    }
    #pragma unroll
    for (int off = 32; off; off >>= 1) s += __shfl_xor(s, off, 64);
    if (lane == 0) yb[idx] = (ushort)f2b(2.0f * s);
}

// Kernel 2: out[64][16384] = x@W^T + y2@B^T.
// 1024 blocks x 256 threads. Block owns 16 output cols (W rows j0..j0+15).
// W staged f32 into LDS in contiguous 1KB/row bursts (DRAM-friendly),
// double-buffered; XOR-swizzled via pre-swizzled global source (rule #21).
// Wave w computes tokens w*16..w*16+15 over full K.
__global__ void __launch_bounds__(256)
lora_gemm(const float* __restrict__ W,      // [16384][4096]
          const float* __restrict__ Bm,     // [16384][64]
          const ushort* __restrict__ xb,    // [64][4096] bf16
          const ushort* __restrict__ yb,    // [64][64] bf16
          float* __restrict__ out) {        // [64][16384]
    __shared__ float lds[2][16 * KT];       // 2 x 16 KB

    const int tid  = threadIdx.x;
    const int w    = tid >> 6;              // wave 0..3 -> token group
    const int lane = tid & 63;
    const int c    = lane & 15;             // frag row/col index
    const int kg   = lane >> 4;             // k-group, offset kg*8
    const int j0   = blockIdx.x << 4;
    const int sw   = (c & 7) << 4;          // read-side swizzle

    const ushort* xrow = xb + (size_t)(w * 16 + c) * 4096 + kg * 8;

    // wave w stages rows w*4 .. w*4+3 of the 16-row W panel (1 KB each).
    // LDS is linear (gload_lds constraint); swizzle applied on the SOURCE:
    // LDS phys byte p holds W[row p/1024][colbyte (p%1024) ^ ((row&7)<<4)].
    auto stage = [&](float* dst, int kt) {
        #pragma unroll
        for (int q = 0; q < 4; ++q) {
            const int r = w * 4 + q;
            const int colb = (lane * 16) ^ ((r & 7) << 4);
            const char* src = (const char*)W +
                ((size_t)(j0 + r) * 4096 + (size_t)kt * KT) * 4 + colb;
            __builtin_amdgcn_global_load_lds((const uint32_t*)src,
                (uint32_t*)((char*)dst + r * 1024), 16, 0, 0);
        }
    };

    f32x4 acc = {0.f, 0.f, 0.f, 0.f};

    stage(lds[0], 0);
    __syncthreads();                         // drains vmcnt: buf0 ready

    for (int t = 0; t < NTILE; ++t) {
        float* lbuf = lds[t & 1];
        if (t + 1 < NTILE) stage(lds[(t + 1) & 1], t + 1);  // prefetch next

        const char* lrow = (const char*)lbuf + c * 1024;
        #pragma unroll
        for (int s = 0; s < 8; ++s) {
            f32x4 b0 = *(const f32x4*)(lrow + s * 128 + ((kg * 32)      ^ sw));
            f32x4 b1 = *(const f32x4*)(lrow + s * 128 + ((kg * 32 + 16) ^ sw));
            bf16x8 bb;
            bb[0] = f2b(b0[0]); bb[1] = f2b(b0[1]);
            bb[2] = f2b(b0[2]); bb[3] = f2b(b0[3]);
            bb[4] = f2b(b1[0]); bb[5] = f2b(b1[1]);
            bb[6] = f2b(b1[2]); bb[7] = f2b(b1[3]);
            bf16x8 aa = *(const bf16x8*)(xrow + t * KT + s * 32);
            acc = __builtin_amdgcn_mfma_f32_16x16x32_bf16(aa, bb, acc, 0, 0, 0);
        }
        __syncthreads();                     // next buf landed; reads done
    }

    // lora tail: 2 K-steps over r=64 with B matrix and y2
    {
        const float*  br = Bm + (size_t)(j0 + c) * 64 + kg * 8;
        const ushort* y0 = yb + (size_t)(w * 16 + c) * 64 + kg * 8;
        #pragma unroll
        for (int k = 0; k < 64; k += 32) {
            f32x4 w0 = *(const f32x4*)(br + k);
            f32x4 w1 = *(const f32x4*)(br + k + 4);
            bf16x8 bb;
            bb[0] = f2b(w0[0]); bb[1] = f2b(w0[1]);
            bb[2] = f2b(w0[2]); bb[3] = f2b(w0[3]);
            bb[4] = f2b(w1[0]); bb[5] = f2b(w1[1]);
            bb[6] = f2b(w1[2]); bb[7] = f2b(w1[3]);
            bf16x8 aa = *(const bf16x8*)(y0 + k);
            acc = __builtin_amdgcn_mfma_f32_16x16x32_bf16(aa, bb, acc, 0, 0, 0);
        }
    }

    // store: token row = w*16 + kg*4 + r, col = j0 + c
    float* op = out + j0 + c;
    #pragma unroll
    for (int r = 0; r < 4; ++r)
        op[(size_t)(w * 16 + kg * 4 + r) * 16384] = acc[r];
}

extern "C" void kernel_launch(void* const* d_in, const int* in_sizes, int n_in,
                              void* d_out, int out_size, void* d_ws, size_t ws_size,
                              hipStream_t stream) {
    const float* x  = (const float*)d_in[0];
    const float* W  = (const float*)d_in[1];
    const float* A  = (const float*)d_in[2];
    const float* Bm = (const float*)d_in[3];
    float* out = (float*)d_out;

    ushort* xb = (ushort*)d_ws;                          // 64*4096*2 = 524288 B
    ushort* yb = (ushort*)((char*)d_ws + 524288);        // 64*64*2   = 8192 B

    prep_kernel<<<1024, 256, 0, stream>>>(x, A, xb, yb);
    lora_gemm<<<1024, 256, 0, stream>>>(W, Bm, xb, yb, out);
}